// Round 6
// baseline (989.174 us; speedup 1.0000x reference)
//
#include <hip/hip_runtime.h>
#include <hip/hip_bf16.h>
#include <cstdint>

#define IN_DIMX 768
#define NTAGS 50
#define NCC 52
#define LSEQ 512
#define BATCH 64
#define START_TAG 50
#define END_TAG 51
#define NEGV (-1000000000.0f)
#define LOG2E 1.4426950408889634f
#define LN2 0.6931471805599453f

// ---------------- GEMM: logits[(b*L+t)*64 + j] = x[b,t,:] . W[j,:] + bias[j] ----
// 8x4 thread tile (1.5 B LDS per FMA), register-prefetch pipeline, XOR-swizzled
// transposed LDS stores (bank-conflict-free: stores 2-way, reads <=2-way, all
// b128-aligned).  BM=64, BK=64, 128 threads, grid 512.
#define GBM 64
#define GBK 64
#define GLDSP 68
#define NKC (IN_DIMX / GBK)   // 12

__global__ __launch_bounds__(128) void gemm_logits(
    const float* __restrict__ x, const float* __restrict__ W,
    const float* __restrict__ bias, float* __restrict__ outL)
{
  __shared__ float xs[GBK][GLDSP];   // [k][m], m-index ^= ((k>>2)&7)<<2
  __shared__ float ws[GBK][GLDSP];   // [k][n], same swizzle
  const int tid = threadIdx.x;       // 0..127
  const size_t row0 = (size_t)blockIdx.x * GBM;
  const int ty = tid >> 4;           // 0..7  : 8 output rows each
  const int tx = tid & 15;           // 0..15 : 4 output cols each
  const int lr = tid >> 4;           // staging row group (0..7)
  const int lk = tid & 15;           // staging float4 index along k
  const int sw = (lk & 7) << 2;      // store-side swizzle for k=lk*4+c

  float acc[8][4] = {};
  float4 xr[8], wr[8];               // prefetch registers (next chunk)

#define LOADCHUNK(KC)                                                          \
  {                                                                            \
    const int kb = (KC) * GBK + lk * 4;                                        \
    _Pragma("unroll")                                                          \
    for (int rr = 0; rr < 8; ++rr) {                                           \
      const int r = lr + rr * 8;                                               \
      xr[rr] = *reinterpret_cast<const float4*>(&x[(row0 + r) * IN_DIMX + kb]);\
    }                                                                          \
    _Pragma("unroll")                                                          \
    for (int rr = 0; rr < 8; ++rr) {                                           \
      const int c = lr + rr * 8;                                               \
      wr[rr] = (c < NTAGS)                                                     \
          ? *reinterpret_cast<const float4*>(&W[c * IN_DIMX + kb])             \
          : make_float4(0.f, 0.f, 0.f, 0.f);                                   \
    }                                                                          \
  }

#define STORECHUNK()                                                           \
  {                                                                            \
    _Pragma("unroll")                                                          \
    for (int rr = 0; rr < 8; ++rr) {                                           \
      const int r = (lr + rr * 8) ^ sw;                                        \
      xs[lk * 4 + 0][r] = xr[rr].x;                                            \
      xs[lk * 4 + 1][r] = xr[rr].y;                                            \
      xs[lk * 4 + 2][r] = xr[rr].z;                                            \
      xs[lk * 4 + 3][r] = xr[rr].w;                                            \
      ws[lk * 4 + 0][r] = wr[rr].x;                                            \
      ws[lk * 4 + 1][r] = wr[rr].y;                                            \
      ws[lk * 4 + 2][r] = wr[rr].z;                                            \
      ws[lk * 4 + 3][r] = wr[rr].w;                                            \
    }                                                                          \
  }

  LOADCHUNK(0)
  STORECHUNK()
  __syncthreads();

  for (int kc = 0; kc < NKC; ++kc) {
    if (kc + 1 < NKC) LOADCHUNK(kc + 1)      // issue early: hide HBM latency

    #pragma unroll
    for (int kk = 0; kk < GBK; ++kk) {
      const int s4 = ((kk >> 2) & 7) << 2;   // read-side swizzle (CSE'd per 4)
      const float4 a0 = *reinterpret_cast<const float4*>(&xs[kk][(ty * 8 + 0) ^ s4]);
      const float4 a1 = *reinterpret_cast<const float4*>(&xs[kk][(ty * 8 + 4) ^ s4]);
      const float4 bq = *reinterpret_cast<const float4*>(&ws[kk][(tx * 4) ^ s4]);
      acc[0][0] += a0.x*bq.x; acc[0][1] += a0.x*bq.y; acc[0][2] += a0.x*bq.z; acc[0][3] += a0.x*bq.w;
      acc[1][0] += a0.y*bq.x; acc[1][1] += a0.y*bq.y; acc[1][2] += a0.y*bq.z; acc[1][3] += a0.y*bq.w;
      acc[2][0] += a0.z*bq.x; acc[2][1] += a0.z*bq.y; acc[2][2] += a0.z*bq.z; acc[2][3] += a0.z*bq.w;
      acc[3][0] += a0.w*bq.x; acc[3][1] += a0.w*bq.y; acc[3][2] += a0.w*bq.z; acc[3][3] += a0.w*bq.w;
      acc[4][0] += a1.x*bq.x; acc[4][1] += a1.x*bq.y; acc[4][2] += a1.x*bq.z; acc[4][3] += a1.x*bq.w;
      acc[5][0] += a1.y*bq.x; acc[5][1] += a1.y*bq.y; acc[5][2] += a1.y*bq.z; acc[5][3] += a1.y*bq.w;
      acc[6][0] += a1.z*bq.x; acc[6][1] += a1.z*bq.y; acc[6][2] += a1.z*bq.z; acc[6][3] += a1.z*bq.w;
      acc[7][0] += a1.w*bq.x; acc[7][1] += a1.w*bq.y; acc[7][2] += a1.w*bq.z; acc[7][3] += a1.w*bq.w;
    }

    if (kc + 1 < NKC) {
      __syncthreads();     // everyone done reading this chunk
      STORECHUNK()
      __syncthreads();     // stores visible before next compute
    }
  }

  #pragma unroll
  for (int i = 0; i < 8; ++i) {
    const int r = ty * 8 + i;
    const int c = tx * 4;
    float4 o;
    o.x = acc[i][0] + ((c + 0) < NTAGS ? bias[c + 0] : 0.f);
    o.y = acc[i][1] + ((c + 1) < NTAGS ? bias[c + 1] : 0.f);
    o.z = acc[i][2] + ((c + 2) < NTAGS ? bias[c + 2] : 0.f);
    o.w = acc[i][3] + ((c + 3) < NTAGS ? bias[c + 3] : 0.f);
    *reinterpret_cast<float4*>(&outL[(row0 + r) * 64 + c]) = o;
  }
}

// ---------------- forward scan in probability space, 1 wave per batch --------
// p[j] = 2^(alpha[j]*log2e - Mc).  Steady state (t>=1): only source rows
// 0..49 can be nonzero (p[START]=p[END]=0 because emission cols 50/51 are NEG
// and row END of exp(T) is all zero).  Transition columns held in 50 NAMED
// float registers (e0..e49) so the compiler cannot demote them to scratch
// (R3 counter evidence: VGPR_Count=36 => array version was NOT in registers).
__device__ __forceinline__ float lane_bcast(float v, int lane) {
  return __int_as_float(__builtin_amdgcn_readlane(__float_as_int(v), lane));
}

#define LA(X) X(0) X(4) X(8) X(12) X(16) X(20) X(24) X(28) X(32) X(36) X(40) X(44) X(48)
#define LB(X) X(1) X(5) X(9) X(13) X(17) X(21) X(25) X(29) X(33) X(37) X(41) X(45) X(49)
#define LC(X) X(2) X(6) X(10) X(14) X(18) X(22) X(26) X(30) X(34) X(38) X(42) X(46)
#define LD(X) X(3) X(7) X(11) X(15) X(19) X(23) X(27) X(31) X(35) X(39) X(43) X(47)
#define L50(X) LA(X) LB(X) LC(X) LD(X)

__global__ __launch_bounds__(64) void crf_scan(
    const float* __restrict__ logits, const int* __restrict__ y,
    const int* __restrict__ lengths, const float* __restrict__ T,
    float* __restrict__ out)
{
  const int b = blockIdx.x;
  const int j = threadIdx.x;                 // 0..63
  const int jj = (j < NCC) ? j : (NCC - 1);
  const bool act = (j < NCC);
  const bool emit = (j < NTAGS);

  // exp2 of scaled transition columns, named registers (SROA-guaranteed).
  #define DECLE(i) const float e##i = act ? exp2f(T[(i) * NCC + jj] * LOG2E) : 0.f;
  L50(DECLE)
  const float eStart = act ? exp2f(T[START_TAG * NCC + jj] * LOG2E) : 0.f;
  const float E2     = act ? exp2f(T[jj * NCC + END_TAG] * LOG2E) : 0.f;

  int len = lengths[b]; if (len < 1) len = 1;
  const float* lrow = logits + (size_t)b * LSEQ * 64;

  // ---- t = 0 peeled: alpha0 is NEG except START=0 -> p = eStart * s0.
  float sCur = emit ? exp2f(lrow[j] * LOG2E) : 0.f;
  float p  = eStart * sCur;          // >0 exactly on lanes 0..49
  float Mc = 0.f;                    // accumulated log2 scale
  float r  = __builtin_amdgcn_rcpf(lane_bcast(p, 0));
  float eN = (emit && 1 < len) ? lrow[64 + j] : 0.f;   // emission for t=1

  for (int t = 1; t < len; ++t) {
    const float scale = (emit ? exp2f(eN * LOG2E) : 0.f) * r;  // off crit path
    const int tn = (t + 1 < len) ? (t + 1) : t;
    eN = emit ? lrow[tn * 64 + j] : 0.f;               // prefetch next step

    float qa = 0.f, qb = 0.f, qc = 0.f, qd = 0.f;
    #define FMA_A(i) qa = fmaf(lane_bcast(p, i), e##i, qa);
    #define FMA_B(i) qb = fmaf(lane_bcast(p, i), e##i, qb);
    #define FMA_C(i) qc = fmaf(lane_bcast(p, i), e##i, qc);
    #define FMA_D(i) qd = fmaf(lane_bcast(p, i), e##i, qd);
    LA(FMA_A)
    LB(FMA_B)
    LC(FMA_C)
    LD(FMA_D)
    const float q = (qa + qb) + (qc + qd);

    Mc -= log2f(r);                  // r is applied this step (lane-uniform)
    p = q * scale;
    r = __builtin_amdgcn_rcpf(lane_bcast(p, 0));  // consumed NEXT step -> hidden
  }

  // all_path = ln2 * (Mc + log2(sum_j p_j * E2_j))
  float v = p * E2;
  #pragma unroll
  for (int off = 32; off; off >>= 1) v += __shfl_xor(v, off, 64);
  const float all_path = (Mc + log2f(v)) * LN2;

  // path score (raw T, raw logits)
  const int* yb = y + b * LSEQ;
  float ps = 0.f;
  for (int t = j; t < len; t += 64) {
    const int yt = yb[t];
    ps += lrow[t * 64 + yt];
    if (t >= 1) ps += T[yb[t - 1] * NCC + yt];
  }
  #pragma unroll
  for (int off = 32; off; off >>= 1) ps += __shfl_xor(ps, off, 64);

  if (j == 0) {
    const float path = ps + T[START_TAG * NCC + yb[0]]
                     + T[yb[len - 1] * NCC + END_TAG];
    atomicAdd(out, (all_path - path) * (1.0f / BATCH));
  }
}

__global__ void zero_out_k(float* o) { o[0] = 0.f; }

extern "C" void kernel_launch(void* const* d_in, const int* in_sizes, int n_in,
                              void* d_out, int out_size, void* d_ws, size_t ws_size,
                              hipStream_t stream) {
  const float* x       = (const float*)d_in[0];
  const int*   y       = (const int*)d_in[1];
  const int*   lengths = (const int*)d_in[2];
  const float* W       = (const float*)d_in[3];
  const float* bias    = (const float*)d_in[4];
  const float* T       = (const float*)d_in[5];
  float* outp   = (float*)d_out;
  float* logits = (float*)d_ws;   // [BATCH*LSEQ][64] fp32, 8.4 MB

  zero_out_k<<<1, 1, 0, stream>>>(outp);
  gemm_logits<<<(BATCH * LSEQ) / GBM, 128, 0, stream>>>(x, W, bias, logits);
  crf_scan<<<BATCH, 64, 0, stream>>>(logits, y, lengths, T, outp);
}

// Round 7
// 482.464 us; speedup vs baseline: 2.0503x; 2.0503x over previous
//
#include <hip/hip_runtime.h>
#include <hip/hip_bf16.h>
#include <cstdint>

#define IN_DIMX 768
#define NTAGS 50
#define NCC 52
#define LSEQ 512
#define BATCH 64
#define START_TAG 50
#define END_TAG 51
#define NEGV (-1000000000.0f)
#define LOG2E 1.4426950408889634f
#define LN2 0.6931471805599453f

// ---------------- GEMM v3: x-broadcast / W-in-registers ----------------------
// Block: 256 thr (4 waves), 64 output rows; lane j owns output column j.
// Per 64-wide k-chunk: x tile [64][64] staged in LDS (linear layout, float4
// stores/loads, conflict-free); waves read x with WAVE-UNIFORM broadcast
// ds_read_b128 (zero bank conflicts by construction); W chunk in 16 float4
// regs per lane (strided global, L2-resident: W is only 150 KB total).
// Register budget ~110 VGPR (R6 lesson: VGPR=256 + 1.17GB WRITE_SIZE = spills).
// One barrier per chunk; xr loads issue pre-compute, ds_write post-compute,
// so the compiler-inserted vmcnt wait lands AFTER ~2048 cy of FMA.
#define NKC (IN_DIMX / 64)   // 12

__global__ __launch_bounds__(256) void gemm_logits(
    const float* __restrict__ x, const float* __restrict__ W,
    const float* __restrict__ bias, float* __restrict__ outL)
{
  __shared__ __align__(16) float xls[2][64][64];
  const int tid = threadIdx.x;
  const int wid = tid >> 6;
  const int j   = tid & 63;
  const size_t row0 = (size_t)blockIdx.x * 64;
  const bool wcol = (j < NTAGS);
  const float biasv = wcol ? bias[j] : 0.f;

  float4 xr[4];
  float4 wv[16];
  float  acc[16];
  #pragma unroll
  for (int r = 0; r < 16; ++r) acc[r] = 0.f;

  // prologue: stage chunk 0 (latency exposed once)
  #pragma unroll
  for (int it = 0; it < 4; ++it) {
    const int O = it * 256 + tid;           // float4 slot: row=O>>4, kq=O&15
    xr[it] = *reinterpret_cast<const float4*>(
        &x[(row0 + (O >> 4)) * IN_DIMX + (O & 15) * 4]);
  }
  #pragma unroll
  for (int it = 0; it < 4; ++it) {
    const int O = it * 256 + tid;
    *reinterpret_cast<float4*>(&xls[0][O >> 4][(O & 15) * 4]) = xr[it];
  }

  for (int c = 0; c < NKC; ++c) {
    // W chunk c -> regs (needed first after barrier -> issue first)
    #pragma unroll
    for (int kq = 0; kq < 16; ++kq)
      wv[kq] = wcol ? *reinterpret_cast<const float4*>(
                          &W[j * IN_DIMX + c * 64 + kq * 4])
                    : make_float4(0.f, 0.f, 0.f, 0.f);
    // x chunk c+1 -> regs (consumed only after compute)
    const int cn = (c + 1 < NKC) ? c + 1 : NKC - 1;
    #pragma unroll
    for (int it = 0; it < 4; ++it) {
      const int O = it * 256 + tid;
      xr[it] = *reinterpret_cast<const float4*>(
          &x[(row0 + (O >> 4)) * IN_DIMX + cn * 64 + (O & 15) * 4]);
    }

    __syncthreads();   // buf[c&1] writes visible; also gates WAR on buf[(c+1)&1]

    const float (*xb)[64] = xls[c & 1];
    const int rbase = wid * 16;
    #pragma unroll
    for (int r = 0; r < 16; ++r) {          // FULL unroll: acc[r] stays static
      float q0 = 0.f, q1 = 0.f, q2 = 0.f, q3 = 0.f;
      #pragma unroll
      for (int kq = 0; kq < 16; ++kq) {     // FULL unroll: wv[kq] stays static
        const float4 xv = *reinterpret_cast<const float4*>(&xb[rbase + r][kq * 4]);
        q0 = fmaf(xv.x, wv[kq].x, q0);
        q1 = fmaf(xv.y, wv[kq].y, q1);
        q2 = fmaf(xv.z, wv[kq].z, q2);
        q3 = fmaf(xv.w, wv[kq].w, q3);
      }
      acc[r] += (q0 + q1) + (q2 + q3);
    }

    // stage chunk c+1 into the other buffer (safe: all waves passed the
    // barrier above only after finishing reads of that parity)
    #pragma unroll
    for (int it = 0; it < 4; ++it) {
      const int O = it * 256 + tid;
      *reinterpret_cast<float4*>(&xls[(c + 1) & 1][O >> 4][(O & 15) * 4]) = xr[it];
    }
  }

  #pragma unroll
  for (int r = 0; r < 16; ++r)
    outL[(row0 + wid * 16 + r) * 64 + j] = acc[r] + biasv;
}

// ---------------- forward scan in probability space, 1 wave per batch --------
// p[j] = 2^(alpha[j]*log2e - Mc).  Recurrence p' = (p . E) * exp2(e) * r with
// lag-1 rescale r = rcp(p[0]) (same r feeds Mc and p -> exact cancel).
// E columns in 50 NAMED registers (R3: VGPR=36 proved arrays were demoted).
// R6 fix: 4-deep emission prefetch (named eA..eD) -- 1-step-ahead (~250 cy)
// cannot cover L2/IF$/HBM latency (~200-900 cy); 4 steps (~1000 cy) can.
__device__ __forceinline__ float lane_bcast(float v, int lane) {
  return __int_as_float(__builtin_amdgcn_readlane(__float_as_int(v), lane));
}

#define LA(X) X(0) X(4) X(8) X(12) X(16) X(20) X(24) X(28) X(32) X(36) X(40) X(44) X(48)
#define LB(X) X(1) X(5) X(9) X(13) X(17) X(21) X(25) X(29) X(33) X(37) X(41) X(45) X(49)
#define LC(X) X(2) X(6) X(10) X(14) X(18) X(22) X(26) X(30) X(34) X(38) X(42) X(46)
#define LD(X) X(3) X(7) X(11) X(15) X(19) X(23) X(27) X(31) X(35) X(39) X(43) X(47)
#define L50(X) LA(X) LB(X) LC(X) LD(X)

__global__ __launch_bounds__(64) void crf_scan(
    const float* __restrict__ logits, const int* __restrict__ y,
    const int* __restrict__ lengths, const float* __restrict__ T,
    float* __restrict__ out)
{
  const int b = blockIdx.x;
  const int j = threadIdx.x;                 // 0..63
  const int jj = (j < NCC) ? j : (NCC - 1);
  const bool act = (j < NCC);
  const bool emit = (j < NTAGS);

  #define DECLE(i) const float e##i = act ? exp2f(T[(i) * NCC + jj] * LOG2E) : 0.f;
  L50(DECLE)
  const float eStart = act ? exp2f(T[START_TAG * NCC + jj] * LOG2E) : 0.f;
  const float E2     = act ? exp2f(T[jj * NCC + END_TAG] * LOG2E) : 0.f;

  int len = lengths[b]; if (len < 1) len = 1;
  const float* lrow = logits + (size_t)b * LSEQ * 64;

  // ---- t = 0 peeled: p = eStart * exp2(e0).
  float p  = eStart * (emit ? exp2f(lrow[j] * LOG2E) : 0.f);
  float Mc = 0.f;
  float r  = __builtin_amdgcn_rcpf(lane_bcast(p, 0));

  // 4-deep emission pipeline (raw logits; exp2 applied at consume time).
  // Loads past len read valid-but-unused buffer entries (t<=511 always).
  float eA = emit ? lrow[1 * 64 + j] : 0.f;
  float eB = emit ? lrow[2 * 64 + j] : 0.f;
  float eC = emit ? lrow[3 * 64 + j] : 0.f;
  float eD = emit ? lrow[4 * 64 + j] : 0.f;

  #define FMA_A(i) qa = fmaf(lane_bcast(p, i), e##i, qa);
  #define FMA_B(i) qb = fmaf(lane_bcast(p, i), e##i, qb);
  #define FMA_C(i) qc = fmaf(lane_bcast(p, i), e##i, qc);
  #define FMA_D(i) qd = fmaf(lane_bcast(p, i), e##i, qd);

  #define STEPX(EREG, TT)                                                     \
  {                                                                           \
    const float scale = (emit ? exp2f((EREG) * LOG2E) : 0.f) * r;             \
    int tl = (TT) + 4; tl = (tl > LSEQ - 1) ? (LSEQ - 1) : tl;                \
    EREG = emit ? lrow[tl * 64 + j] : 0.f;   /* refill 4 ahead */             \
    float qa = 0.f, qb = 0.f, qc = 0.f, qd = 0.f;                             \
    LA(FMA_A) LB(FMA_B) LC(FMA_C) LD(FMA_D)                                   \
    const float q = (qa + qb) + (qc + qd);                                    \
    Mc -= log2f(r);                                                           \
    p = q * scale;                                                            \
    r = __builtin_amdgcn_rcpf(lane_bcast(p, 0));                              \
  }

  int t = 1;
  for (; t + 3 < len; t += 4) {
    STEPX(eA, t)
    STEPX(eB, t + 1)
    STEPX(eC, t + 2)
    STEPX(eD, t + 3)
  }
  if (t     < len) STEPX(eA, t)
  if (t + 1 < len) STEPX(eB, t + 1)
  if (t + 2 < len) STEPX(eC, t + 2)

  // all_path = ln2 * (Mc + log2(sum_j p_j * E2_j))
  float v = p * E2;
  #pragma unroll
  for (int off = 32; off; off >>= 1) v += __shfl_xor(v, off, 64);
  const float all_path = (Mc + log2f(v)) * LN2;

  // path score (raw T, raw logits)
  const int* yb = y + b * LSEQ;
  float ps = 0.f;
  for (int tt = j; tt < len; tt += 64) {
    const int yt = yb[tt];
    ps += lrow[tt * 64 + yt];
    if (tt >= 1) ps += T[yb[tt - 1] * NCC + yt];
  }
  #pragma unroll
  for (int off = 32; off; off >>= 1) ps += __shfl_xor(ps, off, 64);

  if (j == 0) {
    const float path = ps + T[START_TAG * NCC + yb[0]]
                     + T[yb[len - 1] * NCC + END_TAG];
    atomicAdd(out, (all_path - path) * (1.0f / BATCH));
  }
}

__global__ void zero_out_k(float* o) { o[0] = 0.f; }

extern "C" void kernel_launch(void* const* d_in, const int* in_sizes, int n_in,
                              void* d_out, int out_size, void* d_ws, size_t ws_size,
                              hipStream_t stream) {
  const float* x       = (const float*)d_in[0];
  const int*   y       = (const int*)d_in[1];
  const int*   lengths = (const int*)d_in[2];
  const float* W       = (const float*)d_in[3];
  const float* bias    = (const float*)d_in[4];
  const float* T       = (const float*)d_in[5];
  float* outp   = (float*)d_out;
  float* logits = (float*)d_ws;   // [BATCH*LSEQ][64] fp32, 8.4 MB

  zero_out_k<<<1, 1, 0, stream>>>(outp);
  gemm_logits<<<(BATCH * LSEQ) / 64, 256, 0, stream>>>(x, W, bias, logits);
  crf_scan<<<BATCH, 64, 0, stream>>>(logits, y, lengths, T, outp);
}